// Round 8
// baseline (196.634 us; speedup 1.0000x reference)
//
#include <hip/hip_runtime.h>

#define R   256
#define S   128
#define CM  256
#define CH  32
#define CZ  128

typedef __attribute__((ext_vector_type(8))) short short8;
typedef __attribute__((ext_vector_type(4))) float f32x4;
typedef unsigned short ushort_t;

__device__ inline ushort_t f2bf(float f) {
    union { float f; unsigned u; } v; v.f = f;
    unsigned u = v.u;
    unsigned r = u + 0x7FFF + ((u >> 16) & 1);
    return (ushort_t)(r >> 16);
}

// ---------------------------------------------------------------------------
// K0 (merged prep):
//   blocks [0,256):   scale[i*R+j] = 1/(1e-3 + sum_s mask[s,i]*mask[s,j])
//   blocks [256,384): WTp[z][e*32+c] = bf16(w_out[c*32+e][z])
//   blocks [384,448): WcatT[ch][k]   = bf16(ch<32 ? w1[k][ch] : w2[k][ch-32])
// ---------------------------------------------------------------------------
__global__ __launch_bounds__(256) void k_prep(
    const float* __restrict__ mask, const float* __restrict__ w_out,
    const float* __restrict__ w1, const float* __restrict__ w2,
    float* __restrict__ scale, ushort_t* __restrict__ WTp,
    ushort_t* __restrict__ WcatT) {
    int b = blockIdx.x, t = threadIdx.x;
    if (b < 256) {
        int i = b, j = t;
        float acc = 0.f;
        for (int s = 0; s < S; ++s) acc += mask[s * R + i] * mask[s * R + j];
        scale[i * R + j] = 1.0f / (1e-3f + acc);
    } else if (b < 384) {
        int z = b - 256;
        #pragma unroll
        for (int q = 0; q < 4; ++q) {
            int k2 = q * 256 + t;
            int e = k2 >> 5, c = k2 & 31;
            WTp[(size_t)z * 1024 + k2] = f2bf(w_out[(size_t)(c * 32 + e) * CZ + z]);
        }
    } else {
        int ch = b - 384, k = t;
        const float* w = (ch < CH) ? w1 : w2;
        WcatT[(size_t)ch * CM + k] = f2bf(w[(size_t)k * CH + (ch & 31)]);
    }
}

// ---------------------------------------------------------------------------
// K1: LN + both projections via MFMA (validated R3-R7).
// Writes Abig[(r*32+c)][s], BbigT[(r*32+e)][s] (bf16), mask pre-applied.
// ---------------------------------------------------------------------------
__global__ __launch_bounds__(256) void k_lnproj(
    const float* __restrict__ m, const float* __restrict__ mask,
    const float* __restrict__ g, const float* __restrict__ beta,
    const float* __restrict__ b1, const float* __restrict__ b2,
    const ushort_t* __restrict__ WcatT,
    ushort_t* __restrict__ Abig, ushort_t* __restrict__ BbigT) {
    __shared__ ushort_t mnL[64 * CM];
    __shared__ ushort_t wL[64 * CM];
    int t = threadIdx.x;
    int sg = blockIdx.x & 7, rg = blockIdx.x >> 3;
    int s0 = sg * 16, r0 = rg * 4;

    int ml = t >> 2, part = t & 3;
    int r_l = ml >> 4, s_l = ml & 15;
    size_t p = (size_t)(s0 + s_l) * R + (r0 + r_l);
    const float4* row = (const float4*)(m + p * CM + part * 64);
    float4 x[16];
    float sum = 0.f, sq = 0.f;
    #pragma unroll
    for (int i = 0; i < 16; ++i) {
        x[i] = row[i];
        sum += x[i].x + x[i].y + x[i].z + x[i].w;
        sq  += x[i].x * x[i].x + x[i].y * x[i].y
             + x[i].z * x[i].z + x[i].w * x[i].w;
    }
    sum += __shfl_xor(sum, 1); sum += __shfl_xor(sum, 2);
    sq  += __shfl_xor(sq, 1);  sq  += __shfl_xor(sq, 2);
    float mean = sum * (1.0f / CM);
    float var  = sq * (1.0f / CM) - mean * mean;
    float inv  = rsqrtf(var + 1e-5f);
    const float4* g4 = (const float4*)(g + part * 64);
    const float4* be4 = (const float4*)(beta + part * 64);
    #pragma unroll
    for (int c8 = 0; c8 < 8; ++c8) {
        float4 a = x[2 * c8], b = x[2 * c8 + 1];
        float4 ga = g4[2 * c8], gb = g4[2 * c8 + 1];
        float4 ba = be4[2 * c8], bb = be4[2 * c8 + 1];
        union { ushort_t u[8]; uint4 v; } pk;
        pk.u[0] = f2bf((a.x - mean) * inv * ga.x + ba.x);
        pk.u[1] = f2bf((a.y - mean) * inv * ga.y + ba.y);
        pk.u[2] = f2bf((a.z - mean) * inv * ga.z + ba.z);
        pk.u[3] = f2bf((a.w - mean) * inv * ga.w + ba.w);
        pk.u[4] = f2bf((b.x - mean) * inv * gb.x + bb.x);
        pk.u[5] = f2bf((b.y - mean) * inv * gb.y + bb.y);
        pk.u[6] = f2bf((b.z - mean) * inv * gb.z + bb.z);
        pk.u[7] = f2bf((b.w - mean) * inv * gb.w + bb.w);
        int ck = part * 8 + c8;
        int phys = ck ^ (ml & 15);
        *(uint4*)&mnL[ml * CM + phys * 8] = pk.v;
    }
    #pragma unroll
    for (int it = 0; it < 8; ++it) {
        int v = t + it * 256;
        int ch = v >> 5, ck = v & 31;
        int phys = ck ^ (ch & 15);
        *(uint4*)&wL[ch * CM + phys * 8] =
            *(const uint4*)&WcatT[(size_t)ch * CM + ck * 8];
    }
    __syncthreads();

    int w = t >> 6, lane = t & 63, quad = lane >> 4, l15 = lane & 15;
    int ch = w * 16 + l15;
    f32x4 acc[4];
    #pragma unroll
    for (int a = 0; a < 4; a++) acc[a] = (f32x4)(0.f);
    #pragma unroll
    for (int ks = 0; ks < 8; ++ks) {
        int cb = ks * 4 + quad;
        short8 bfr = *(const short8*)&wL[ch * CM + ((cb ^ l15) << 3)];
        #pragma unroll
        for (int mt = 0; mt < 4; ++mt) {
            int mm = mt * 16 + l15;
            short8 afr = *(const short8*)&mnL[mm * CM + ((cb ^ l15) << 3)];
            acc[mt] = __builtin_amdgcn_mfma_f32_16x16x32_bf16(afr, bfr, acc[mt], 0, 0, 0);
        }
    }

    int c = ch & 31;
    float bias = (ch < CH) ? b1[c] : b2[c];
    ushort_t* dst = (ch < CH) ? Abig : BbigT;
    #pragma unroll
    for (int mt = 0; mt < 4; ++mt) {
        int r = r0 + mt;
        union { ushort_t u[4]; uint2 v; } pk;
        #pragma unroll
        for (int reg = 0; reg < 4; ++reg) {
            int s = s0 + quad * 4 + reg;
            float mv = mask[(size_t)s * R + r];
            pk.u[reg] = f2bf((acc[mt][reg] + bias) * mv);
        }
        *(uint2*)&dst[((size_t)r * CH + c) * S + s0 + quad * 4] = pk.v;
    }
}

// ---------------------------------------------------------------------------
// K2: FUSED outer-product + projection, v3 (LDS-traffic-minimized).
// Block = 8 i x 8 j = 64 pairs, 256 threads (4 waves).
//   Stage-1: wave w owns i_l = 2w, 2w+1 (A-frags in regs, 64 VGPR);
//            computes (2i x 32c) x (8j x 4e) per ec; 4x B multiread (was 8x).
//   Stage-2: 2-D partition: wave = (pair-half pg = w>>1, z-half zg = w&1):
//            32 pairs x 64 z; oc multiread 2x (was 8x); wf from L1/L2.
//   Single 8 KB B buffer (writes sit between barrier-2 and barrier-1: safe).
// LDS/block: 24 KB; ~704 KB moved (vs 1.7 MB in v2).
// ---------------------------------------------------------------------------
__global__ __launch_bounds__(256) void k_fuse(
    const ushort_t* __restrict__ Abig, const ushort_t* __restrict__ BbigT,
    const ushort_t* __restrict__ WTp, const float* __restrict__ b_out,
    const float* __restrict__ scale, float* __restrict__ out) {
    __shared__ ushort_t oc[64 * 128];        // 16 KB: [pair][k2-local] swizzled
    __shared__ ushort_t shB[32 * 128];       // 8 KB:  [el*8+j][s] swizzled
    int t = threadIdx.x;
    int w = t >> 6, lane = t & 63, quad = lane >> 4, l15 = lane & 15;
    int ib = blockIdx.x >> 5, jb = blockIdx.x & 31;

    // ---- stage-1 A-frags: wave owns rows (ib*8 + 2w)*32 .. +64 ----
    short8 af[4][4];
    int ibase = (ib * 8 + w * 2) * 32;
    #pragma unroll
    for (int mt = 0; mt < 4; ++mt)
        #pragma unroll
        for (int ks = 0; ks < 4; ++ks)
            af[mt][ks] = *(const short8*)
                &Abig[(size_t)(ibase + mt * 16 + l15) * S + ks * 32 + quad * 8];

    // ---- B staging: thread owns rows r2a, r2a+16, chunk cka ----
    int r2a = t >> 4, cka = t & 15;
    const ushort_t* gB0 = BbigT
        + ((size_t)jb * 256 + (r2a & 7) * 32 + (r2a >> 3)) * S + cka * 8;
    const ushort_t* gB1 = BbigT
        + ((size_t)jb * 256 + (r2a & 7) * 32 + (r2a >> 3) + 2) * S + cka * 8;
    ushort_t* bd0 = &shB[r2a * 128 + ((cka ^ (r2a & 15)) << 3)];
    ushort_t* bd1 = &shB[(r2a + 16) * 128 + ((cka ^ ((r2a + 16) & 15)) << 3)];
    uint4 breg0 = *(const uint4*)&gB0[0];    // prefetch ec=0 (+4 e <=> +512)
    uint4 breg1 = *(const uint4*)&gB1[0];

    // ---- stage-2 roles: pg = pair-half, zg = z-half ----
    int pg = w >> 1, zg = w & 1;
    const ushort_t* Wp = WTp + (size_t)(zg * 64 + l15) * 1024 + quad * 8;

    f32x4 acc2[2][4];
    #pragma unroll
    for (int a = 0; a < 2; a++)
        #pragma unroll
        for (int b = 0; b < 4; b++) acc2[a][b] = (f32x4)(0.f);

    for (int ec = 0; ec < 8; ++ec) {
        *(uint4*)bd0 = breg0;
        *(uint4*)bd1 = breg1;
        if (ec < 7) {
            breg0 = *(const uint4*)&gB0[(ec + 1) * 512];
            breg1 = *(const uint4*)&gB1[(ec + 1) * 512];
        }
        __syncthreads();   // B published; prev stage-2 oc reads complete

        // ---- stage-1: (2i x 32c) x (8j x 4e), K = 128 ----
        f32x4 acc1[4][2];
        #pragma unroll
        for (int a = 0; a < 4; a++)
            #pragma unroll
            for (int b = 0; b < 2; b++) acc1[a][b] = (f32x4)(0.f);
        #pragma unroll
        for (int ks = 0; ks < 4; ++ks) {
            int chq = ks * 4 + quad;
            int r20 = l15, r21 = 16 + l15;
            short8 bf0 = *(const short8*)
                &shB[r20 * 128 + ((chq ^ (r20 & 15)) << 3)];
            short8 bf1 = *(const short8*)
                &shB[r21 * 128 + ((chq ^ (r21 & 15)) << 3)];
            #pragma unroll
            for (int mt = 0; mt < 4; ++mt) {
                acc1[mt][0] = __builtin_amdgcn_mfma_f32_16x16x32_bf16(
                    af[mt][ks], bf0, acc1[mt][0], 0, 0, 0);
                acc1[mt][1] = __builtin_amdgcn_mfma_f32_16x16x32_bf16(
                    af[mt][ks], bf1, acc1[mt][1], 0, 0, 0);
            }
        }
        // pack to oc: lane's 4 regs = 4 consecutive c at (pair pp, e)
        #pragma unroll
        for (int mt = 0; mt < 4; ++mt) {
            int i_l = w * 2 + (mt >> 1);
            int pp = i_l * 8 + (l15 & 7);
            int c0 = (mt & 1) * 16 + quad * 4;
            #pragma unroll
            for (int nt = 0; nt < 2; ++nt) {
                int el = nt * 2 + (l15 >> 3);
                int k2l = el * 32 + c0;
                int cc = k2l >> 3;
                union { ushort_t u[4]; uint2 v; } pk;
                #pragma unroll
                for (int reg = 0; reg < 4; ++reg)
                    pk.u[reg] = f2bf(acc1[mt][nt][reg]);
                *(uint2*)((char*)oc + pp * 256 + ((cc ^ (pp & 7)) << 4)
                          + ((quad & 1) << 3)) = pk.v;
            }
        }
        __syncthreads();   // oc published; all B reads done
        // ---- stage-2: (32 pairs x 64 z) += oc x WTp over this k2 chunk ----
        #pragma unroll
        for (int ksl = 0; ksl < 4; ++ksl) {
            int cc2 = ksl * 4 + quad;
            short8 a2[2];
            #pragma unroll
            for (int pt = 0; pt < 2; ++pt) {
                int pp = pg * 32 + pt * 16 + l15;
                a2[pt] = *(const short8*)
                    ((const char*)oc + pp * 256 + ((cc2 ^ (pp & 7)) << 4));
            }
            #pragma unroll
            for (int nt = 0; nt < 4; ++nt) {
                short8 wf = *(const short8*)
                    &Wp[(size_t)nt * 16 * 1024 + ec * 128 + ksl * 32];
                #pragma unroll
                for (int pt = 0; pt < 2; ++pt)
                    acc2[pt][nt] = __builtin_amdgcn_mfma_f32_16x16x32_bf16(
                        a2[pt], wf, acc2[pt][nt], 0, 0, 0);
            }
        }
    }

    // ---- epilogue: bias + 1/(eps+norm) scale ----
    float bz[4];
    #pragma unroll
    for (int nt = 0; nt < 4; ++nt) bz[nt] = b_out[zg * 64 + nt * 16 + l15];
    #pragma unroll
    for (int pt = 0; pt < 2; ++pt) {
        #pragma unroll
        for (int reg = 0; reg < 4; ++reg) {
            int p = pg * 32 + pt * 16 + quad * 4 + reg;
            int pg_glob = (ib * 8 + (p >> 3)) * R + jb * 8 + (p & 7);
            float sc = scale[pg_glob];
            #pragma unroll
            for (int nt = 0; nt < 4; ++nt) {
                int z = zg * 64 + nt * 16 + l15;
                out[(size_t)pg_glob * CZ + z] = (acc2[pt][nt][reg] + bz[nt]) * sc;
            }
        }
    }
}

// ---------------------------------------------------------------------------
extern "C" void kernel_launch(void* const* d_in, const int* in_sizes, int n_in,
                              void* d_out, int out_size, void* d_ws, size_t ws_size,
                              hipStream_t stream) {
    const float* m    = (const float*)d_in[0];
    const float* mask = (const float*)d_in[1];
    const float* g    = (const float*)d_in[2];
    const float* be   = (const float*)d_in[3];
    const float* w1   = (const float*)d_in[4];
    const float* b1   = (const float*)d_in[5];
    const float* w2   = (const float*)d_in[6];
    const float* b2   = (const float*)d_in[7];
    const float* wo   = (const float*)d_in[8];
    const float* bo   = (const float*)d_in[9];
    float* out = (float*)d_out;

    char* ws = (char*)d_ws;
    ushort_t* Abig  = (ushort_t*)ws;                        // 2 MB
    ushort_t* BbigT = Abig + (size_t)R * CH * S;            // 2 MB
    ushort_t* WTp   = BbigT + (size_t)R * CH * S;           // 256 KB
    ushort_t* WcatT = WTp + (size_t)CZ * CH * CH;           // 32 KB
    float*    scale = (float*)(WcatT + (size_t)64 * CM);    // 256 KB

    k_prep<<<448, 256, 0, stream>>>(mask, wo, w1, w2, scale, WTp, WcatT);
    k_lnproj<<<512, 256, 0, stream>>>(m, mask, g, be, b1, b2, WcatT, Abig, BbigT);
    k_fuse<<<1024, 256, 0, stream>>>(Abig, BbigT, WTp, bo, scale, out);
}

// Round 9
// 185.916 us; speedup vs baseline: 1.0576x; 1.0576x over previous
//
#include <hip/hip_runtime.h>

#define R   256
#define S   128
#define CM  256
#define CH  32
#define CZ  128

typedef __attribute__((ext_vector_type(8))) short short8;
typedef __attribute__((ext_vector_type(4))) float f32x4;
typedef unsigned short ushort_t;

__device__ inline ushort_t f2bf(float f) {
    union { float f; unsigned u; } v; v.f = f;
    unsigned u = v.u;
    unsigned r = u + 0x7FFF + ((u >> 16) & 1);
    return (ushort_t)(r >> 16);
}

// ---------------------------------------------------------------------------
// K0 (merged prep):
//   blocks [0,256):   scale[i*R+j] = 1/(1e-3 + sum_s mask[s,i]*mask[s,j])
//   blocks [256,384): WTp[z][e*32+c] = bf16(w_out[c*32+e][z])
//   blocks [384,448): WcatT[ch][k]   = bf16(ch<32 ? w1[k][ch] : w2[k][ch-32])
// ---------------------------------------------------------------------------
__global__ __launch_bounds__(256) void k_prep(
    const float* __restrict__ mask, const float* __restrict__ w_out,
    const float* __restrict__ w1, const float* __restrict__ w2,
    float* __restrict__ scale, ushort_t* __restrict__ WTp,
    ushort_t* __restrict__ WcatT) {
    int b = blockIdx.x, t = threadIdx.x;
    if (b < 256) {
        int i = b, j = t;
        float acc = 0.f;
        for (int s = 0; s < S; ++s) acc += mask[s * R + i] * mask[s * R + j];
        scale[i * R + j] = 1.0f / (1e-3f + acc);
    } else if (b < 384) {
        int z = b - 256;
        #pragma unroll
        for (int q = 0; q < 4; ++q) {
            int k2 = q * 256 + t;
            int e = k2 >> 5, c = k2 & 31;
            WTp[(size_t)z * 1024 + k2] = f2bf(w_out[(size_t)(c * 32 + e) * CZ + z]);
        }
    } else {
        int ch = b - 384, k = t;
        const float* w = (ch < CH) ? w1 : w2;
        WcatT[(size_t)ch * CM + k] = f2bf(w[(size_t)k * CH + (ch & 31)]);
    }
}

// ---------------------------------------------------------------------------
// K1: LN + both projections via MFMA (validated R3-R8).
// Writes Abig[(r*32+c)][s], BbigT[(r*32+e)][s] (bf16), mask pre-applied.
// ---------------------------------------------------------------------------
__global__ __launch_bounds__(256) void k_lnproj(
    const float* __restrict__ m, const float* __restrict__ mask,
    const float* __restrict__ g, const float* __restrict__ beta,
    const float* __restrict__ b1, const float* __restrict__ b2,
    const ushort_t* __restrict__ WcatT,
    ushort_t* __restrict__ Abig, ushort_t* __restrict__ BbigT) {
    __shared__ ushort_t mnL[64 * CM];
    __shared__ ushort_t wL[64 * CM];
    int t = threadIdx.x;
    int sg = blockIdx.x & 7, rg = blockIdx.x >> 3;
    int s0 = sg * 16, r0 = rg * 4;

    int ml = t >> 2, part = t & 3;
    int r_l = ml >> 4, s_l = ml & 15;
    size_t p = (size_t)(s0 + s_l) * R + (r0 + r_l);
    const float4* row = (const float4*)(m + p * CM + part * 64);
    float4 x[16];
    float sum = 0.f, sq = 0.f;
    #pragma unroll
    for (int i = 0; i < 16; ++i) {
        x[i] = row[i];
        sum += x[i].x + x[i].y + x[i].z + x[i].w;
        sq  += x[i].x * x[i].x + x[i].y * x[i].y
             + x[i].z * x[i].z + x[i].w * x[i].w;
    }
    sum += __shfl_xor(sum, 1); sum += __shfl_xor(sum, 2);
    sq  += __shfl_xor(sq, 1);  sq  += __shfl_xor(sq, 2);
    float mean = sum * (1.0f / CM);
    float var  = sq * (1.0f / CM) - mean * mean;
    float inv  = rsqrtf(var + 1e-5f);
    const float4* g4 = (const float4*)(g + part * 64);
    const float4* be4 = (const float4*)(beta + part * 64);
    #pragma unroll
    for (int c8 = 0; c8 < 8; ++c8) {
        float4 a = x[2 * c8], b = x[2 * c8 + 1];
        float4 ga = g4[2 * c8], gb = g4[2 * c8 + 1];
        float4 ba = be4[2 * c8], bb = be4[2 * c8 + 1];
        union { ushort_t u[8]; uint4 v; } pk;
        pk.u[0] = f2bf((a.x - mean) * inv * ga.x + ba.x);
        pk.u[1] = f2bf((a.y - mean) * inv * ga.y + ba.y);
        pk.u[2] = f2bf((a.z - mean) * inv * ga.z + ba.z);
        pk.u[3] = f2bf((a.w - mean) * inv * ga.w + ba.w);
        pk.u[4] = f2bf((b.x - mean) * inv * gb.x + bb.x);
        pk.u[5] = f2bf((b.y - mean) * inv * gb.y + bb.y);
        pk.u[6] = f2bf((b.z - mean) * inv * gb.z + bb.z);
        pk.u[7] = f2bf((b.w - mean) * inv * gb.w + bb.w);
        int ck = part * 8 + c8;
        int phys = ck ^ (ml & 15);
        *(uint4*)&mnL[ml * CM + phys * 8] = pk.v;
    }
    #pragma unroll
    for (int it = 0; it < 8; ++it) {
        int v = t + it * 256;
        int ch = v >> 5, ck = v & 31;
        int phys = ck ^ (ch & 15);
        *(uint4*)&wL[ch * CM + phys * 8] =
            *(const uint4*)&WcatT[(size_t)ch * CM + ck * 8];
    }
    __syncthreads();

    int w = t >> 6, lane = t & 63, quad = lane >> 4, l15 = lane & 15;
    int ch = w * 16 + l15;
    f32x4 acc[4];
    #pragma unroll
    for (int a = 0; a < 4; a++) acc[a] = (f32x4)(0.f);
    #pragma unroll
    for (int ks = 0; ks < 8; ++ks) {
        int cb = ks * 4 + quad;
        short8 bfr = *(const short8*)&wL[ch * CM + ((cb ^ l15) << 3)];
        #pragma unroll
        for (int mt = 0; mt < 4; ++mt) {
            int mm = mt * 16 + l15;
            short8 afr = *(const short8*)&mnL[mm * CM + ((cb ^ l15) << 3)];
            acc[mt] = __builtin_amdgcn_mfma_f32_16x16x32_bf16(afr, bfr, acc[mt], 0, 0, 0);
        }
    }

    int c = ch & 31;
    float bias = (ch < CH) ? b1[c] : b2[c];
    ushort_t* dst = (ch < CH) ? Abig : BbigT;
    #pragma unroll
    for (int mt = 0; mt < 4; ++mt) {
        int r = r0 + mt;
        union { ushort_t u[4]; uint2 v; } pk;
        #pragma unroll
        for (int reg = 0; reg < 4; ++reg) {
            int s = s0 + quad * 4 + reg;
            float mv = mask[(size_t)s * R + r];
            pk.u[reg] = f2bf((acc[mt][reg] + bias) * mv);
        }
        *(uint2*)&dst[((size_t)r * CH + c) * S + s0 + quad * 4] = pk.v;
    }
}

// ---------------------------------------------------------------------------
// K2: FUSED outer+projection v4 = R7-v2 shape (512 thr, 8 waves) +
//   (a) double-buffered oc AND shB -> ONE barrier per ec (was 2),
//   (b) stage-2 2-D partition: wave = (pair-half, z-quarter) = 32p x 32z:
//       oc LDS multiread 8x -> 4x; wf lane-streams stay line-sequential.
// Per-iter hazards all barrier-separated:
//   iter e: stage1(e): R shB[e&1], W oc[e&1]
//           stage2(e-1): R oc[(e-1)&1]
//           Bwrite(e+1): W shB[(e+1)&1]      -> barrier
// ---------------------------------------------------------------------------
__global__ __launch_bounds__(512) void k_fuse(
    const ushort_t* __restrict__ Abig, const ushort_t* __restrict__ BbigT,
    const ushort_t* __restrict__ WTp, const float* __restrict__ b_out,
    const float* __restrict__ scale, float* __restrict__ out) {
    __shared__ ushort_t oc[2][64 * 128];     // 2 x 16 KB
    __shared__ ushort_t shB[2][32 * 128];    // 2 x 8 KB
    int t = threadIdx.x;
    int w = t >> 6, lane = t & 63, quad = lane >> 4, l15 = lane & 15;
    int ib = blockIdx.x >> 5, jb = blockIdx.x & 31;
    int i_g = ib * 8 + w;
    int jj = l15 & 7, elb = l15 >> 3;

    // stage-1 A-frags: wave owns i-strip i_g (register-resident)
    short8 af[2][4];
    #pragma unroll
    for (int mt = 0; mt < 2; ++mt)
        #pragma unroll
        for (int ks = 0; ks < 4; ++ks)
            af[mt][ks] = *(const short8*)
                &Abig[((size_t)i_g * 32 + mt * 16 + l15) * S + ks * 32 + quad * 8];

    // B staging: thread owns LDS row r2 = t>>4 (0..31), 16B chunk ck = t&15
    int r2 = t >> 4, ck = t & 15;
    const ushort_t* gB = BbigT
        + ((size_t)jb * 256 + (r2 & 7) * 32 + (r2 >> 3)) * S + ck * 8;
    int boff = r2 * 128 + ((ck ^ (r2 & 15)) << 3);

    // stage-2 roles: pair-half pg2, z-quarter zq
    int pg2 = w >> 2, zq = w & 3;
    const ushort_t* Wp = WTp + (size_t)(zq * 32 + l15) * 1024 + quad * 8;
    int pwr = w * 8 + jj;                    // oc pair-row written in stage-1

    f32x4 acc2[2][2];
    #pragma unroll
    for (int a = 0; a < 2; a++)
        #pragma unroll
        for (int b = 0; b < 2; b++) acc2[a][b] = (f32x4)(0.f);

    auto stage2 = [&](int ee) {
        const ushort_t* ob = oc[ee & 1];
        #pragma unroll
        for (int ksl = 0; ksl < 4; ++ksl) {
            int cc2 = ksl * 4 + quad;
            short8 a2[2];
            #pragma unroll
            for (int mt = 0; mt < 2; ++mt) {
                int pp = pg2 * 32 + mt * 16 + l15;
                a2[mt] = *(const short8*)
                    ((const char*)ob + pp * 256 + ((cc2 ^ (pp & 7)) << 4));
            }
            #pragma unroll
            for (int nt = 0; nt < 2; ++nt) {
                short8 wf = *(const short8*)
                    &Wp[(size_t)(nt * 16) * 1024 + ee * 128 + ksl * 32];
                #pragma unroll
                for (int mt = 0; mt < 2; ++mt)
                    acc2[mt][nt] = __builtin_amdgcn_mfma_f32_16x16x32_bf16(
                        a2[mt], wf, acc2[mt][nt], 0, 0, 0);
            }
        }
    };

    // prologue: stage B(0); prefetch B(1)
    uint4 breg = *(const uint4*)&gB[0];
    *(uint4*)&shB[0][boff] = breg;
    breg = *(const uint4*)&gB[512];
    __syncthreads();

    for (int ec = 0; ec < 8; ++ec) {
        int buf = ec & 1;
        // ---- stage-1: (1i x 32c) x (8j x 4e), K = 128 ----
        f32x4 acc1[2][2];
        #pragma unroll
        for (int a = 0; a < 2; a++)
            #pragma unroll
            for (int b = 0; b < 2; b++) acc1[a][b] = (f32x4)(0.f);
        #pragma unroll
        for (int ks = 0; ks < 4; ++ks) {
            int chq = ks * 4 + quad;
            int r20 = l15, r21 = 16 + l15;
            short8 bf0 = *(const short8*)
                &shB[buf][r20 * 128 + ((chq ^ (r20 & 15)) << 3)];
            short8 bf1 = *(const short8*)
                &shB[buf][r21 * 128 + ((chq ^ (r21 & 15)) << 3)];
            #pragma unroll
            for (int mt = 0; mt < 2; ++mt) {
                acc1[mt][0] = __builtin_amdgcn_mfma_f32_16x16x32_bf16(
                    af[mt][ks], bf0, acc1[mt][0], 0, 0, 0);
                acc1[mt][1] = __builtin_amdgcn_mfma_f32_16x16x32_bf16(
                    af[mt][ks], bf1, acc1[mt][1], 0, 0, 0);
            }
        }
        // pack to oc[buf]
        #pragma unroll
        for (int mt = 0; mt < 2; ++mt) {
            int c00 = mt * 16 + quad * 4;
            #pragma unroll
            for (int nt = 0; nt < 2; ++nt) {
                int el = nt * 2 + elb;
                int k2l = el * 32 + c00;
                int cc = k2l >> 3;
                union { ushort_t u[4]; uint2 v; } pk;
                #pragma unroll
                for (int reg = 0; reg < 4; ++reg)
                    pk.u[reg] = f2bf(acc1[mt][nt][reg]);
                *(uint2*)((char*)oc[buf] + pwr * 256 + ((cc ^ (pwr & 7)) << 4)
                          + ((k2l & 7) << 1)) = pk.v;
            }
        }
        // ---- stage-2 of previous chunk (overlaps barrier pressure) ----
        if (ec > 0) stage2(ec - 1);
        // ---- stage B(ec+1) into the other buffer; prefetch B(ec+2) ----
        if (ec < 7) {
            *(uint4*)&shB[(ec + 1) & 1][boff] = breg;
            if (ec < 6) breg = *(const uint4*)&gB[(ec + 2) * 512];
        }
        __syncthreads();
    }
    stage2(7);

    // ---- epilogue: bias + 1/(eps+norm) scale ----
    float bz[2];
    #pragma unroll
    for (int nt = 0; nt < 2; ++nt) bz[nt] = b_out[zq * 32 + nt * 16 + l15];
    #pragma unroll
    for (int mt = 0; mt < 2; ++mt) {
        #pragma unroll
        for (int reg = 0; reg < 4; ++reg) {
            int p = pg2 * 32 + mt * 16 + quad * 4 + reg;
            int pg_glob = (ib * 8 + (p >> 3)) * R + jb * 8 + (p & 7);
            float sc = scale[pg_glob];
            #pragma unroll
            for (int nt = 0; nt < 2; ++nt) {
                int z = zq * 32 + nt * 16 + l15;
                out[(size_t)pg_glob * CZ + z] = (acc2[mt][nt][reg] + bz[nt]) * sc;
            }
        }
    }
}

// ---------------------------------------------------------------------------
extern "C" void kernel_launch(void* const* d_in, const int* in_sizes, int n_in,
                              void* d_out, int out_size, void* d_ws, size_t ws_size,
                              hipStream_t stream) {
    const float* m    = (const float*)d_in[0];
    const float* mask = (const float*)d_in[1];
    const float* g    = (const float*)d_in[2];
    const float* be   = (const float*)d_in[3];
    const float* w1   = (const float*)d_in[4];
    const float* b1   = (const float*)d_in[5];
    const float* w2   = (const float*)d_in[6];
    const float* b2   = (const float*)d_in[7];
    const float* wo   = (const float*)d_in[8];
    const float* bo   = (const float*)d_in[9];
    float* out = (float*)d_out;

    char* ws = (char*)d_ws;
    ushort_t* Abig  = (ushort_t*)ws;                        // 2 MB
    ushort_t* BbigT = Abig + (size_t)R * CH * S;            // 2 MB
    ushort_t* WTp   = BbigT + (size_t)R * CH * S;           // 256 KB
    ushort_t* WcatT = WTp + (size_t)CZ * CH * CH;           // 32 KB
    float*    scale = (float*)(WcatT + (size_t)64 * CM);    // 256 KB

    k_prep<<<448, 256, 0, stream>>>(mask, wo, w1, w2, scale, WTp, WcatT);
    k_lnproj<<<512, 256, 0, stream>>>(m, mask, g, be, b1, b2, WcatT, Abig, BbigT);
    k_fuse<<<1024, 512, 0, stream>>>(Abig, BbigT, WTp, bo, scale, out);
}